// Round 4
// baseline (176.879 us; speedup 1.0000x reference)
//
#include <hip/hip_runtime.h>
#include <math.h>

#define NB 8      // NUM_BATCHES
#define C  256    // channels
#define CR 64     // C / r

#define POOL_BLOCKS  512
#define SCALE_BLOCKS 2048

typedef float vf4 __attribute__((ext_vector_type(4)));

// ---------------------------------------------------------------------------
// Kernel 1: per-batch partial sums + counts. One wave per 4-row group
// (4 KB contiguous streaming). bid is wave-uniform -> scalar compare gives a
// 0/1 mask; accumulate is branch-free predicated FMA into vf4 acc[8] (pure
// VGPRs). CACHED loads (not nontemporal): x must land in L3 so scale_kernel
// can re-read it from Infinity Cache instead of HBM.
// ---------------------------------------------------------------------------
__global__ __launch_bounds__(256) void pool_kernel(
    const float* __restrict__ x,         // [N, 256]
    const int*   __restrict__ bids,      // [N]
    float*       __restrict__ partials,  // [POOL_BLOCKS][2048]
    float*       __restrict__ cpart,     // [POOL_BLOCKS][8]
    int N)
{
    __shared__ float lsum[4][NB][C];   // 32 KB
    __shared__ float lcnt[4][NB];

    const int tid  = threadIdx.x;
    const int wid  = tid >> 6;
    const int lane = tid & 63;

    vf4   acc[NB];
    float cnt[NB];
    #pragma unroll
    for (int b = 0; b < NB; ++b) { acc[b] = (vf4){0.f,0.f,0.f,0.f}; cnt[b] = 0.f; }

    const int gwave   = blockIdx.x * 4 + wid;
    const int totw    = POOL_BLOCKS * 4;
    const int ngroups = N >> 2;

    for (int g = gwave; g < ngroups; g += totw) {
        const size_t r0 = (size_t)g * 4;
        const int b0 = __builtin_amdgcn_readfirstlane(bids[r0 + 0]);
        const int b1 = __builtin_amdgcn_readfirstlane(bids[r0 + 1]);
        const int b2 = __builtin_amdgcn_readfirstlane(bids[r0 + 2]);
        const int b3 = __builtin_amdgcn_readfirstlane(bids[r0 + 3]);
        const vf4 v0 = ((const vf4*)(x + (r0 + 0) * C))[lane];
        const vf4 v1 = ((const vf4*)(x + (r0 + 1) * C))[lane];
        const vf4 v2 = ((const vf4*)(x + (r0 + 2) * C))[lane];
        const vf4 v3 = ((const vf4*)(x + (r0 + 3) * C))[lane];
        #pragma unroll
        for (int b = 0; b < NB; ++b) {
            const float m0 = (b0 == b) ? 1.f : 0.f;
            const float m1 = (b1 == b) ? 1.f : 0.f;
            const float m2 = (b2 == b) ? 1.f : 0.f;
            const float m3 = (b3 == b) ? 1.f : 0.f;
            acc[b] += v0 * m0;
            acc[b] += v1 * m1;
            acc[b] += v2 * m2;
            acc[b] += v3 * m3;
            cnt[b] += m0 + m1 + m2 + m3;
        }
    }
    // leftover rows if N % 4 != 0 (none at N=262144) — wave 0 handles them
    if (gwave == 0) {
        for (int row = ngroups * 4; row < N; ++row) {
            const int bb = __builtin_amdgcn_readfirstlane(bids[row]);
            const vf4 v = ((const vf4*)(x + (size_t)row * C))[lane];
            #pragma unroll
            for (int b = 0; b < NB; ++b) {
                const float m = (bb == b) ? 1.f : 0.f;
                acc[b] += v * m;
                cnt[b] += m;
            }
        }
    }

    // one conflict-free b128 LDS write per batch per lane
    #pragma unroll
    for (int b = 0; b < NB; ++b)
        ((vf4*)&lsum[wid][b][0])[lane] = acc[b];
    if (lane == 0) {
        #pragma unroll
        for (int b = 0; b < NB; ++b) lcnt[wid][b] = cnt[b];
    }
    __syncthreads();

    float* pout = partials + (size_t)blockIdx.x * (NB * C);
    for (int i = tid; i < NB * C; i += 256)
        pout[i] = lsum[0][0][i] + lsum[1][0][i] + lsum[2][0][i] + lsum[3][0][i];
    if (tid < NB)
        cpart[blockIdx.x * NB + tid] =
            lcnt[0][tid] + lcnt[1][tid] + lcnt[2][tid] + lcnt[3][tid];
}

// ---------------------------------------------------------------------------
// Kernel 2: tree-reduce the per-block partials. 64 blocks: blockIdx = jp*8+jo;
// block sums 64 partial rows over its 256-col chunk (coalesced 1 KB reads).
// jo==0 blocks also reduce the count partials.
// ---------------------------------------------------------------------------
__global__ __launch_bounds__(256) void reduce_kernel(
    const float* __restrict__ partials,  // [POOL_BLOCKS][2048]
    const float* __restrict__ cpart,     // [POOL_BLOCKS][8]
    float*       __restrict__ partial2,  // [8][2048]
    float*       __restrict__ c2)        // [8][8]
{
    const int jo  = blockIdx.x & 7;   // column chunk
    const int jp  = blockIdx.x >> 3;  // partial-row chunk (64 rows each)
    const int col = jo * 256 + threadIdx.x;
    const int PR  = POOL_BLOCKS / 8;  // 64 rows per jp

    float s = 0.f;
    #pragma unroll 8
    for (int p = 0; p < PR; ++p)
        s += partials[(size_t)(jp * PR + p) * (NB * C) + col];
    partial2[jp * (NB * C) + col] = s;

    if (jo == 0 && threadIdx.x < NB) {
        float c = 0.f;
        for (int p = 0; p < PR; ++p)
            c += cpart[(jp * PR + p) * NB + threadIdx.x];
        c2[jp * NB + threadIdx.x] = c;
    }
}

// ---------------------------------------------------------------------------
// Kernel 3: final reduce + tiny MLP. pooled = sums/max(cnt,1);
// h = relu(pooled@W1+b1); y = sigmoid(h@W2+b2). One block, 256 threads.
// ---------------------------------------------------------------------------
__global__ __launch_bounds__(256) void mlp_kernel(
    const float* __restrict__ partial2,  // [8][2048]
    const float* __restrict__ c2,        // [8][8]
    const float* __restrict__ W1,        // [256][64]
    const float* __restrict__ b1,        // [64]
    const float* __restrict__ W2,        // [64][256]
    const float* __restrict__ b2,        // [256]
    float*       __restrict__ y)         // [8][256] out
{
    __shared__ float pooled[NB][C];
    __shared__ float h[NB][CR];
    __shared__ float cnts[NB];
    const int tid = threadIdx.x;

    if (tid < NB) {
        float c = 0.f;
        #pragma unroll
        for (int j = 0; j < 8; ++j) c += c2[j * NB + tid];
        cnts[tid] = fmaxf(c, 1.f);
    }
    __syncthreads();

    for (int i = tid; i < NB * C; i += 256) {
        float s = 0.f;
        #pragma unroll
        for (int j = 0; j < 8; ++j) s += partial2[j * (NB * C) + i];
        (&pooled[0][0])[i] = s / cnts[i >> 8];
    }
    __syncthreads();

    // h: 8*64 = 512 outputs, 2 per thread
    for (int o = tid; o < NB * CR; o += 256) {
        const int b = o >> 6, j = o & 63;
        float acc = b1[j];
        #pragma unroll 4
        for (int k = 0; k < C; ++k) acc = fmaf(pooled[b][k], W1[k * CR + j], acc);
        (&h[0][0])[o] = fmaxf(acc, 0.f);
    }
    __syncthreads();

    // y: 8*256 = 2048 outputs, 8 per thread
    for (int o = tid; o < NB * C; o += 256) {
        const int b = o >> 8, j = o & 255;
        float acc = b2[j];
        #pragma unroll
        for (int k = 0; k < CR; ++k) acc = fmaf(h[b][k], W2[k * C + j], acc);
        y[o] = 1.f / (1.f + __expf(-acc));
    }
}

// ---------------------------------------------------------------------------
// Kernel 4: out[row,:] = y[bids[row],:] * x[row,:].
// REVERSED iteration order: pool read x forward, so the most-recently-cached
// rows (highest indices) are re-read FIRST -> stack-order re-access gives
// ~95% Infinity-Cache hits (268 MB working set vs 256 MB L3; forward re-scan
// would be the cyclic-LRU pathology = ~0% hits). x loads are CACHED;
// out stores stay nontemporal so the write stream doesn't evict x.
// ---------------------------------------------------------------------------
__global__ __launch_bounds__(256) void scale_kernel(
    const float* __restrict__ x,     // [N, 256]
    const int*   __restrict__ bids,  // [N]
    const float* __restrict__ y,     // [8][256]
    float*       __restrict__ out,   // [N, 256]
    int N)
{
    __shared__ float ly[NB][C];      // 8 KB
    const int tid = threadIdx.x;
    for (int i = tid; i < NB * C; i += 256) (&ly[0][0])[i] = y[i];
    __syncthreads();

    const int wid  = tid >> 6;
    const int lane = tid & 63;
    const int gwave   = blockIdx.x * 4 + wid;
    const int totw    = SCALE_BLOCKS * 4;
    const int ngroups = N >> 2;

    // leftover rows first (they were pooled last -> hottest in cache)
    if (gwave == 0) {
        for (int row = N - 1; row >= ngroups * 4; --row) {
            const int bb = __builtin_amdgcn_readfirstlane(bids[row]);
            const vf4 v  = ((const vf4*)(x + (size_t)row * C))[lane];
            const vf4 gg = ((const vf4*)&ly[bb][0])[lane];
            ((vf4*)(out + (size_t)row * C))[lane] = v * gg;
        }
    }

    for (int g = ngroups - 1 - gwave; g >= 0; g -= totw) {
        const size_t r0 = (size_t)g * 4;
        const int b0 = __builtin_amdgcn_readfirstlane(bids[r0 + 0]);
        const int b1 = __builtin_amdgcn_readfirstlane(bids[r0 + 1]);
        const int b2 = __builtin_amdgcn_readfirstlane(bids[r0 + 2]);
        const int b3 = __builtin_amdgcn_readfirstlane(bids[r0 + 3]);
        const vf4 v0 = ((const vf4*)(x + (r0 + 0) * C))[lane];
        const vf4 v1 = ((const vf4*)(x + (r0 + 1) * C))[lane];
        const vf4 v2 = ((const vf4*)(x + (r0 + 2) * C))[lane];
        const vf4 v3 = ((const vf4*)(x + (r0 + 3) * C))[lane];
        const vf4 g0 = ((const vf4*)&ly[b0][0])[lane];
        const vf4 g1 = ((const vf4*)&ly[b1][0])[lane];
        const vf4 g2 = ((const vf4*)&ly[b2][0])[lane];
        const vf4 g3 = ((const vf4*)&ly[b3][0])[lane];
        __builtin_nontemporal_store(v0 * g0, ((vf4*)(out + (r0 + 0) * C)) + lane);
        __builtin_nontemporal_store(v1 * g1, ((vf4*)(out + (r0 + 1) * C)) + lane);
        __builtin_nontemporal_store(v2 * g2, ((vf4*)(out + (r0 + 2) * C)) + lane);
        __builtin_nontemporal_store(v3 * g3, ((vf4*)(out + (r0 + 3) * C)) + lane);
    }
}

extern "C" void kernel_launch(void* const* d_in, const int* in_sizes, int n_in,
                              void* d_out, int out_size, void* d_ws, size_t ws_size,
                              hipStream_t stream)
{
    const float* x    = (const float*)d_in[0];
    const int*   bids = (const int*)  d_in[1];
    const float* W1   = (const float*)d_in[2];
    const float* b1   = (const float*)d_in[3];
    const float* W2   = (const float*)d_in[4];
    const float* b2   = (const float*)d_in[5];
    float* out = (float*)d_out;

    const int N = in_sizes[1];           // 262144

    // ws layout (floats), all regions fully written before read each call:
    // partials[512*2048] | cpart[512*8] | partial2[8*2048] | c2[64] | gy[2048]
    float* partials = (float*)d_ws;
    float* cpart    = partials + POOL_BLOCKS * (NB * C);
    float* partial2 = cpart + POOL_BLOCKS * NB;
    float* c2       = partial2 + 8 * (NB * C);
    float* gy       = c2 + 64;

    pool_kernel  <<<POOL_BLOCKS, 256, 0, stream>>>(x, bids, partials, cpart, N);
    reduce_kernel<<<64, 256, 0, stream>>>(partials, cpart, partial2, c2);
    mlp_kernel   <<<1, 256, 0, stream>>>(partial2, c2, W1, b1, W2, b2, gy);
    scale_kernel <<<SCALE_BLOCKS, 256, 0, stream>>>(x, bids, gy, out, N);
}